// Round 6
// baseline (18615.787 us; speedup 1.0000x reference)
//
#include <hip/hip_runtime.h>
#include <hip/hip_bf16.h>

typedef __bf16 bf16;
typedef __bf16 bf16x8 __attribute__((ext_vector_type(8)));
typedef float floatx4 __attribute__((ext_vector_type(4)));
typedef unsigned int uint;
typedef __attribute__((address_space(1))) void gvoid;
typedef __attribute__((address_space(3))) void lvoid;

#define MFMA16(a, b, c) __builtin_amdgcn_mfma_f32_16x16x32_bf16((a), (b), (c), 0, 0, 0)
#define NB_REC 64

// ---------------------------------------------------------------------------
// Grid-wide barrier over NB_REC co-resident blocks (1 block/CU: ~106KB LDS).
// Monotonic counter/generation; targets carried across launches (no reuse).
// ---------------------------------------------------------------------------
__device__ __forceinline__ void grid_sync(uint* region, uint target) {
    __syncthreads();
    if (threadIdx.x == 0) {
        __threadfence();
        uint old = atomicAdd(region, 1u);
        if (old == target * NB_REC - 1) {
            __hip_atomic_store(region + 16, target, __ATOMIC_RELEASE, __HIP_MEMORY_SCOPE_AGENT);
        } else {
            while (__hip_atomic_load(region + 16, __ATOMIC_ACQUIRE, __HIP_MEMORY_SCOPE_AGENT) < target) {
                __builtin_amdgcn_s_sleep(2);
            }
        }
        __threadfence();
    }
    __syncthreads();
}

__global__ void k_cvt(const float* __restrict__ src, bf16* __restrict__ dst, int n) {
    int idx = blockIdx.x * 256 + threadIdx.x;
    if (idx < n) dst[idx] = (bf16)src[idx];
}

// Transpose fp32 (B,T,D) -> (t*32+b, D) bf16; zero 3 barrier regions.
__global__ void k_prep(const float* __restrict__ inp, bf16* __restrict__ xT,
                       uint* __restrict__ bar) {
    size_t idx = (size_t)blockIdx.x * 256 + threadIdx.x;
    if (blockIdx.x == 0 && threadIdx.x < 96) bar[threadIdx.x] = 0;
    int d = (int)(idx & 255);
    int t = (int)((idx >> 8) & 511);
    int b = (int)(idx >> 17);
    xT[((size_t)(t * 32 + b) << 8) | d] = (bf16)inp[idx];
}

__global__ void k_movmean(const bf16* __restrict__ xT, bf16* __restrict__ out,
                          int s) {
    size_t idx = (size_t)blockIdx.x * 256 + threadIdx.x;
    int d = (int)(idx & 255);
    int m = (int)(idx >> 8);
    int t = m >> 5, b = m & 31;
    float acc = 0.f;
    for (int i = 0; i < s; ++i)
        acc += (float)xT[(((size_t)(t + i) * 32 + b) << 8) | d];
    out[idx] = (bf16)(acc * (1.f / (float)s));
}

// ---------------------------------------------------------------------------
// Tiled MFMA GEMM, 128x128 tile, BK=64, global_load_lds(16B) staging with
// XOR chunk swizzle (chunk q of row m at q^(m&7)). C = A1·W1^T (+ A2·W2^T)
// + biases (fp32). Cf!=null: fp32 out; else bf16 Cb. Stores guarded (Mstore).
// ---------------------------------------------------------------------------
__global__ __launch_bounds__(256, 2) void k_gemm(
    const bf16* __restrict__ A1, int lda1, const bf16* __restrict__ W1, int nk1,
    const bf16* __restrict__ A2, int lda2, const bf16* __restrict__ W2, int nk2,
    const float* __restrict__ bias1, const float* __restrict__ bias2,
    float* __restrict__ Cf, bf16* __restrict__ Cb, int ldc, int Mstore) {
    __shared__ bf16 lsA[128 * 64];
    __shared__ bf16 lsW[128 * 64];
    const int tid = threadIdx.x;
    const int lane = tid & 63, w = tid >> 6;
    const int quad = lane >> 4, lr = lane & 15;
    const int wm = w >> 1, wn = w & 1;
    const int m0 = blockIdx.y * 128, n0 = blockIdx.x * 128;

    floatx4 acc[4][4] = {};

    const bf16* As[2] = {A1, A2};
    const bf16* Ws[2] = {W1, W2};
    const int ldas[2] = {lda1, lda2};
    const int nks[2] = {nk1, nk2};

    for (int ph = 0; ph < 2; ++ph) {
        const int nk = nks[ph];
        if (nk == 0) continue;
        const bf16* A = As[ph];
        const bf16* Wp = Ws[ph];
        const int lda = ldas[ph];
        const int ldw = nk * 64;
        for (int kb = 0; kb < nk; ++kb) {
            const bf16* Ab = A + (size_t)m0 * lda + (size_t)kb * 64;
            const bf16* Wb = Wp + (size_t)n0 * ldw + (size_t)kb * 64;
#pragma unroll
            for (int i = 0; i < 4; ++i) {
                int c = (i * 4 + w) * 64 + lane;
                int m = c >> 3, q = c & 7;
                const bf16* g1 = Ab + (size_t)m * lda + ((q ^ (m & 7)) << 3);
                __builtin_amdgcn_global_load_lds((const gvoid*)g1,
                                                 (lvoid*)(lsA + (i * 4 + w) * 512), 16, 0, 0);
                const bf16* g2 = Wb + (size_t)m * ldw + ((q ^ (m & 7)) << 3);
                __builtin_amdgcn_global_load_lds((const gvoid*)g2,
                                                 (lvoid*)(lsW + (i * 4 + w) * 512), 16, 0, 0);
            }
            __syncthreads();
#pragma unroll
            for (int s = 0; s < 2; ++s) {
                bf16x8 af[4], bfr[4];
#pragma unroll
                for (int i = 0; i < 4; ++i) {
                    int kc = s * 4 + quad;
                    int m = wm * 64 + i * 16 + lr;
                    af[i] = *(const bf16x8*)(lsA + m * 64 + ((kc ^ (m & 7)) << 3));
                    int n = wn * 64 + i * 16 + lr;
                    bfr[i] = *(const bf16x8*)(lsW + n * 64 + ((kc ^ (n & 7)) << 3));
                }
#pragma unroll
                for (int i = 0; i < 4; ++i)
#pragma unroll
                    for (int j = 0; j < 4; ++j)
                        acc[i][j] = MFMA16(af[i], bfr[j], acc[i][j]);
            }
            __syncthreads();
        }
    }

    // Epilogue (C/D layout: col = lane&15, row = quad*4 + reg).
#pragma unroll
    for (int j = 0; j < 4; ++j) {
        int col = n0 + wn * 64 + j * 16 + lr;
        float bs = 0.f;
        if (bias1) bs += bias1[col];
        if (bias2) bs += bias2[col];
#pragma unroll
        for (int i = 0; i < 4; ++i) {
            int rowb = m0 + wm * 64 + i * 16 + quad * 4;
#pragma unroll
            for (int r = 0; r < 4; ++r) {
                int row = rowb + r;
                if (row < Mstore) {
                    float v = acc[i][j][r] + bs;
                    if (Cf) Cf[(size_t)row * ldc + col] = v;
                    else    Cb[(size_t)row * ldc + col] = (bf16)v;
                }
            }
        }
    }
}

// ---------------------------------------------------------------------------
// Persistent GRU recurrence over a chunk of T steps. 64 blocks x 384 threads
// (6 waves = 2 Mtiles x 3 gates). Block blk owns hidden cols [blk*16,+16).
// Whh slice (48x1024 bf16, rows padded +8 -> 2-way banks) resident in LDS.
// h double-buffered bf16 in global; fp32 h master in registers, carried
// across chunk launches through fp32 hf. One grid barrier per step; targets
// monotonic from tgt0. hid_out (final h) is fp32 (d_out dtype).
// ---------------------------------------------------------------------------
__global__ __launch_bounds__(384, 1) void k_rec(
    const float* __restrict__ G, const bf16* __restrict__ Whh,
    const float* __restrict__ bhh, bf16* __restrict__ outs,
    bf16* __restrict__ h01, float* __restrict__ hf,
    float* __restrict__ hid_out, uint* __restrict__ bar,
    int T, int init, int final_, uint tgt0) {
    const int tid = threadIdx.x, blk = blockIdx.x;
    const int lane = tid & 63, w = tid >> 6;
    const int quad = lane >> 4, lr = lane & 15;
    const int mi = (w >= 3) ? 1 : 0, ni = w - mi * 3;

    __shared__ bf16 lw[48 * 1032];
    __shared__ float gh_s[3 * 32 * 17];
    __shared__ float lbhh[48];

    for (int c = tid; c < 48 * 128; c += 384) {
        int row = c >> 7, q = c & 127;
        int grow = (row >> 4) * 1024 + blk * 16 + (row & 15);
        *(bf16x8*)(&lw[row * 1032 + q * 8]) =
            *(const bf16x8*)(Whh + (size_t)grow * 1024 + q * 8);
    }
    if (tid < 48) lbhh[tid] = bhh[(tid >> 4) * 1024 + blk * 16 + (tid & 15)];

    float hreg[2] = {0.f, 0.f};
    if (tid < 256) {
        int b = tid >> 4, c = tid & 15, cg = blk * 16 + c;
#pragma unroll
        for (int pp = 0; pp < 2; ++pp) {
            float h = init ? 0.f : hf[(size_t)(b + pp * 16) * 1024 + cg];
            hreg[pp] = h;
            h01[(size_t)(b + pp * 16) * 1024 + cg] = (bf16)h;
        }
    }
    uint tgt = tgt0;
    grid_sync(bar, tgt++);

    for (int t = 0; t < T; ++t) {
        const bf16* hb = h01 + (size_t)(t & 1) * (32 * 1024);
        bf16* hn = h01 + (size_t)((t + 1) & 1) * (32 * 1024);

        floatx4 acc = {0.f, 0.f, 0.f, 0.f};
        const bf16* aptr = hb + (size_t)(mi * 16 + lr) * 1024 + quad * 8;
        const bf16* bptr = &lw[(ni * 16 + lr) * 1032 + quad * 8];
#pragma unroll 8
        for (int kt = 0; kt < 32; ++kt) {
            bf16x8 av = *(const bf16x8*)(aptr + kt * 32);
            bf16x8 bv = *(const bf16x8*)(bptr + kt * 32);
            acc = MFMA16(av, bv, acc);
        }
#pragma unroll
        for (int r = 0; r < 4; ++r)
            gh_s[(ni * 32 + mi * 16 + quad * 4 + r) * 17 + lr] = acc[r];
        __syncthreads();

        if (tid < 256) {
#pragma unroll
            for (int pp = 0; pp < 2; ++pp) {
                int b = (tid >> 4) + pp * 16;
                int c = tid & 15;
                int cg = blk * 16 + c;
                const float* Grow = G + ((size_t)t * 32 + b) * 3072;
                float Gr = Grow[cg];
                float Gi = Grow[1024 + cg];
                float Gn = Grow[2048 + cg];
                float ghr = gh_s[b * 17 + c] + lbhh[c];
                float ghi = gh_s[(32 + b) * 17 + c] + lbhh[16 + c];
                float ghn = gh_s[(64 + b) * 17 + c] + lbhh[32 + c];
                float rg = 1.f / (1.f + __expf(-(Gr + ghr)));
                float ig = 1.f / (1.f + __expf(-(Gi + ghi)));
                float pre = Gn + rg * ghn;
                float e2 = __expf(2.f * pre);
                float ng = 1.f - 2.f / (e2 + 1.f);  // tanh(pre)
                float h = hreg[pp];
                h = ng + ig * (h - ng);
                hreg[pp] = h;
                bf16 hv = (bf16)h;
                hn[(size_t)b * 1024 + cg] = hv;
                outs[((size_t)t * 32 + b) * 1024 + cg] = hv;
            }
        }
        grid_sync(bar, tgt++);
    }

    if (tid < 256) {
        int b = tid >> 4, c = tid & 15, cg = blk * 16 + c;
#pragma unroll
        for (int pp = 0; pp < 2; ++pp) {
            hf[(size_t)(b + pp * 16) * 1024 + cg] = hreg[pp];
            if (final_)
                hid_out[(size_t)(b + pp * 16) * 1024 + cg] = hreg[pp];
        }
    }
}

// ---------------------------------------------------------------------------
extern "C" void kernel_launch(void* const* d_in, const int* in_sizes, int n_in,
                              void* d_out, int out_size, void* d_ws, size_t ws_size,
                              hipStream_t stream) {
    const float* inp  = (const float*)d_in[0];
    const float* Wxh0 = (const float*)d_in[1];
    const float* bxh0 = (const float*)d_in[2];
    const float* Whh0 = (const float*)d_in[3];
    const float* bhh0 = (const float*)d_in[4];
    const float* Wnh0 = (const float*)d_in[5];
    const float* bnh0 = (const float*)d_in[6];
    const float* Wxh1 = (const float*)d_in[7];
    const float* bxh1 = (const float*)d_in[8];
    const float* Whh1 = (const float*)d_in[9];
    const float* bhh1 = (const float*)d_in[10];
    const float* Wnh1 = (const float*)d_in[11];
    const float* bnh1 = (const float*)d_in[12];
    const float* Wxh2 = (const float*)d_in[13];
    const float* bxh2 = (const float*)d_in[14];
    const float* Whh2 = (const float*)d_in[15];
    const float* bhh2 = (const float*)d_in[16];
    const float* Wnh2 = (const float*)d_in[17];
    const float* bnh2 = (const float*)d_in[18];
    const float* Wout = (const float*)d_in[19];
    const float* bout = (const float*)d_in[20];
    float* out = (float*)d_out;  // reference output dtype is float32

    char* ws = (char*)d_ws;
    size_t o = 0;
    auto take = [&](size_t bytes) {
        o = (o + 255) & ~(size_t)255;
        char* p = ws + o;
        o += bytes;
        return p;
    };
    const size_t RP = 16512;  // row padding: covers GEMM A-tile overread
    bf16* xT    = (bf16*)take(RP * 256 * 2);
    bf16* ms1   = (bf16*)take(RP * 256 * 2);
    bf16* ms2   = (bf16*)take(RP * 256 * 2);
    bf16* outs0 = (bf16*)take(RP * 1024 * 2);
    bf16* outs1 = (bf16*)take(RP * 1024 * 2);
    bf16* outs2 = outs0;  // alias: outs0 dead after proj0 (launched first)
    bf16* h01   = (bf16*)take((size_t)2 * 32 * 1024 * 2);
    float* hf   = (float*)take((size_t)32 * 1024 * 4);
    uint* bar   = (uint*)take((size_t)3 * 32 * 4);
    bf16* wXh = (bf16*)take((size_t)3072 * 1024 * 2);
    bf16* wNh = (bf16*)take((size_t)3072 * 256 * 2);
    bf16* wHh = (bf16*)take((size_t)3072 * 1024 * 2);
    bf16* wOut = (bf16*)take((size_t)256 * 1024 * 2);
    o = (o + 255) & ~(size_t)255;

    size_t avail = (ws_size > o) ? (ws_size - o) : 0;
    int CT = (int)(avail / ((size_t)32 * 3072 * 4));
    if (CT > 512) CT = 512;
    if (CT < 4) CT = 4;
    float* G = (float*)(ws + o);
    (void)in_sizes; (void)n_in; (void)out_size;

    const size_t o0 = 0, o1 = (size_t)512 * 32 * 256, o2 = o1 + (size_t)511 * 32 * 256;
    const size_t ohid = o2 + (size_t)509 * 32 * 256;

    auto cvt = [&](const float* s, bf16* d, int n) {
        k_cvt<<<(n + 255) / 256, 256, 0, stream>>>(s, d, n);
    };
    cvt(Wout, wOut, 256 * 1024);
    k_prep<<<16384, 256, 0, stream>>>(inp, xT, bar);
    k_movmean<<<511 * 32, 256, 0, stream>>>(xT, ms1, 2);
    k_movmean<<<509 * 32, 256, 0, stream>>>(xT, ms2, 4);

    auto run_layer = [&](const bf16* xs, int ldx, const float* Wxh, int nkx,
                         const bf16* ms, const float* Wnh,
                         const float* bxh, const float* bnh,
                         const float* Whh, const float* bhh,
                         bf16* outs, float* hid, int T, int layer) {
        cvt(Wxh, wXh, 3072 * nkx * 64);
        cvt(Wnh, wNh, 3072 * 256);
        cvt(Whh, wHh, 3072 * 1024);
        uint base = 0;
        for (int t0 = 0; t0 < T; t0 += CT) {
            int ct = (T - t0 < CT) ? (T - t0) : CT;
            int gy = (ct * 32 + 127) / 128;
            k_gemm<<<dim3(24, gy), 256, 0, stream>>>(
                xs + (size_t)t0 * 32 * ldx, ldx, wXh, nkx,
                ms + (size_t)t0 * 32 * 256, 256, wNh, 4,
                bxh, bnh, G, (bf16*)nullptr, 3072, ct * 32);
            k_rec<<<NB_REC, 384, 0, stream>>>(
                G, wHh, bhh, outs + (size_t)t0 * 32 * 1024, h01, hf, hid,
                bar + 32 * layer, ct, (t0 == 0) ? 1 : 0, (t0 + ct >= T) ? 1 : 0,
                base + 1);
            base += (uint)ct + 1;
        }
    };

    // Layer 0 (ms0 == x): G = x@Wxh0^T + x@Wnh0^T + bxh0 + bnh0
    run_layer(xT, 256, Wxh0, 4, xT, Wnh0, bxh0, bnh0, Whh0, bhh0,
              outs0, out + ohid, 512, 0);
    // Layer 1: xs = outs0[1:], ms = ms1
    run_layer(outs0 + (size_t)32 * 1024, 1024, Wxh1, 16, ms1, Wnh1,
              bxh1, bnh1, Whh1, bhh1, outs1, out + ohid + 32768, 511, 1);
    // Projection of layer-0 outs BEFORE layer 2 overwrites the aliased buffer.
    k_gemm<<<dim3(2, 128), 256, 0, stream>>>(outs0, 1024, wOut, 16,
                                             nullptr, 0, nullptr, 0, bout, nullptr,
                                             out + o0, nullptr, 256, 16384);
    // Layer 2: xs = outs1[2:], ms = ms2; outs2 aliases outs0.
    run_layer(outs1 + (size_t)64 * 1024, 1024, Wxh2, 16, ms2, Wnh2,
              bxh2, bnh2, Whh2, bhh2, outs2, out + ohid + 65536, 509, 2);

    k_gemm<<<dim3(2, 128), 256, 0, stream>>>(outs1, 1024, wOut, 16,
                                             nullptr, 0, nullptr, 0, bout, nullptr,
                                             out + o1, nullptr, 256, 16352);
    k_gemm<<<dim3(2, 128), 256, 0, stream>>>(outs2, 1024, wOut, 16,
                                             nullptr, 0, nullptr, 0, bout, nullptr,
                                             out + o2, nullptr, 256, 16288);
}